// Round 1
// baseline (1310.902 us; speedup 1.0000x reference)
//
#include <hip/hip_runtime.h>
#include <stdint.h>

// Softmax-Viterbi forward, 1024x1024 grid, S=4, via strip-pipelined wavefront.
//
// Domain transform: W = log2(e) * V. Then
//   W[i,j,t] = log2( sum_s 2^( W_src[s] + A'[t,s] ) ) + th'[t]
// with A' = A*log2e, th' = theta*log2e (folded in via fmaf at load time).
// Each cell carries (w0..w3, m=max_s w_s); lse offset = source cell's m
// (exact math, prevents exp2 overflow; args <= max A' ~ 8).
//
// Mapping: 64 blocks x 64 threads (1 wave). Wave owns 16 rows (quad=row,
// lane&3 = target state). Skewed schedule: quad q computes column
// j = tau - q + 1 at step tau. Cross-quad via shfl; strip boundary rows go
// through a global buffer with column-progress flags (release/acquire,
// agent scope -> correct across XCDs).

#define NN 1024
#define MM 1024
#define LOG2E 1.4426950408889634f
#define LN2f  0.6931471805599453f
#define NEG_S (-1.4426950408889634e8f)   // log2e * (-1e8): boundary value in scaled domain
#define CH 8                              // steps per chunk (= post granularity)
#define NCH 130                           // ceil((MM+15)/CH): tau = 0..1039 covers j up to MM for quad 15

__global__ __launch_bounds__(64, 1) void viterbi_pipe(
    const float* __restrict__ theta, const float* __restrict__ A,
    float* __restrict__ out, float* __restrict__ bnd, int* __restrict__ prog)
{
    const int lane = threadIdx.x & 63;
    const int quad = lane >> 2;           // row within strip (0..15)
    const int t    = lane & 3;            // target state (m,x,y,s)
    const int bid  = blockIdx.x;
    // adjacent strips on same XCD (blocks 8 apart share an XCD)
    const int strip = ((bid & 7) << 3) | (bid >> 3);
    const int r = (strip << 4) + quad;    // 0-based theta/A row for this lane
    const bool isCons = (strip > 0);
    const bool isProd = (strip < 63);

    const float4* A4 = (const float4*)A;
    // flat index magic: (r*MM + c)*4 + t works for both A (in float4 units) and theta (floats)
    const size_t baseA = ((size_t)r * MM) * 4 + t;
    const float4* B4 = (const float4*)bnd + (size_t)(strip - 1) * MM;  // consumer boundary rows
    float* Pst = bnd + (size_t)strip * MM * 4;                          // producer boundary rows
    int* myflag = prog + strip * 32;          // 128B-strided flags (avoid line contention)
    int* upflag = prog + (strip - 1) * 32;

    // cell state: own quad's last cell (vleft), quad-above current (vup), quad-above prev (vdiag)
    float wq0=NEG_S,wq1=NEG_S,wq2=NEG_S,wq3=NEG_S,mq=NEG_S;
    float up0=NEG_S,up1=NEG_S,up2=NEG_S,up3=NEG_S,mu=NEG_S;
    float dg0=NEG_S,dg1=NEG_S,dg2=NEG_S,dg3=NEG_S,md=NEG_S;
    if (strip == 0 && quad == 0) { dg0=dg1=dg2=dg3=0.f; md=0.f; }   // V[0,0] = 0

    float4 abuf[CH]; float tbuf[CH];      // A row (4 floats) + theta, prefetched 1 chunk ahead
    float4 bw[CH];   float bmx[CH];       // boundary cells for quad 0 (cols 8cc+2+u)

    // prefetch chunk 0 A/theta (consumed at tau = u; col c = tau - quad, clamped; masked later)
#pragma unroll
    for (int u = 0; u < CH; ++u) {
        int c = u - quad; c = c < 0 ? 0 : c;
        abuf[u] = A4[baseA + (size_t)c * 4];
        tbuf[u] = theta[baseA + (size_t)c * 4];
    }
    if (isCons) {
        // need boundary cols 1..9 -> producer bottom row >= col 9
        while (__hip_atomic_load(upflag, __ATOMIC_ACQUIRE, __HIP_MEMORY_SCOPE_AGENT) < 9)
            __builtin_amdgcn_s_sleep(1);
        float4 b1 = B4[0];                 // col 1: initial vup for quad 0
        if (quad == 0) {
            up0=b1.x; up1=b1.y; up2=b1.z; up3=b1.w;
            mu = fmaxf(fmaxf(b1.x,b1.y), fmaxf(b1.z,b1.w));
        }
#pragma unroll
        for (int u = 0; u < CH; ++u) bw[u] = B4[(2 + u) - 1];
#pragma unroll
        for (int u = 0; u < CH; ++u)
            bmx[u] = fmaxf(fmaxf(bw[u].x,bw[u].y), fmaxf(bw[u].z,bw[u].w));
    }

    const int baseLane = lane & 60;

    for (int cc = 0; cc < NCH; ++cc) {
#pragma unroll
        for (int u = 0; u < CH; ++u) {
            const int tau = (cc << 3) + u;
            const int jq  = tau - quad + 1;            // my column (1-based)
            // select source cell per target: m,s -> diag; x -> up; y -> left
            float s0 = (t==2)?wq0:((t==1)?up0:dg0);
            float s1 = (t==2)?wq1:((t==1)?up1:dg1);
            float s2 = (t==2)?wq2:((t==1)?up2:dg2);
            float s3 = (t==2)?wq3:((t==1)?up3:dg3);
            float off= (t==2)?mq :((t==1)?mu :md );
            float4 a = abuf[u];
            float e0 = exp2f(fmaf(a.x, LOG2E, s0 - off));
            float e1 = exp2f(fmaf(a.y, LOG2E, s1 - off));
            float e2 = exp2f(fmaf(a.z, LOG2E, s2 - off));
            float e3 = exp2f(fmaf(a.w, LOG2E, s3 - off));
            float L  = log2f((e0+e1)+(e2+e3));
            float wn = fmaf(tbuf[u], LOG2E, off + L);
            wn = (jq >= 1 && jq <= MM) ? wn : NEG_S;   // outside interior -> boundary value
            // collect quad's 4 states into every lane + running max
            float w0 = __shfl(wn, baseLane);
            float w1 = __shfl(wn, baseLane+1);
            float w2 = __shfl(wn, baseLane+2);
            float w3 = __shfl(wn, baseLane+3);
            float mn = fmaxf(fmaxf(w0,w1), fmaxf(w2,w3));
            // bottom row: publish boundary cell / final answer
            if (quad == 15 && jq >= 1 && jq <= MM) {
                if (isProd) {
                    Pst[(size_t)(jq-1)*4 + t] = wn;    // 4 lanes -> contiguous 16B record
                } else if (jq == MM) {
                    float ans = LN2f * (mn + log2f(exp2f(w0-mn)+exp2f(w1-mn)
                                                 +exp2f(w2-mn)+exp2f(w3-mn)));
                    if (t == 0) out[0] = ans;
                }
            }
            // advance: vdiag <- vup; vup <- row above's new cell (or boundary for quad 0)
            dg0=up0; dg1=up1; dg2=up2; dg3=up3; md=mu;
            up0=__shfl_up(w0,4); up1=__shfl_up(w1,4);
            up2=__shfl_up(w2,4); up3=__shfl_up(w3,4);
            mu =__shfl_up(mn,4);
            if (quad == 0) {
                if (isCons) { float4 b = bw[u]; up0=b.x; up1=b.y; up2=b.z; up3=b.w; mu=bmx[u]; }
                else        { up0=NEG_S; up1=NEG_S; up2=NEG_S; up3=NEG_S; mu=NEG_S; }
            }
            wq0=w0; wq1=w1; wq2=w2; wq3=w3; mq=mn;
        }
        // post progress: bottom row has completed columns <= 8cc-7.
        // (all prior-chunk loads already consumed -> the release's vmcnt drain only
        //  covers our small stores; next chunk's loads are issued AFTER it)
        if (isProd) {
            int done = (cc << 3) - 7;
            if (done >= 8 && lane == 0)
                __hip_atomic_store(myflag, done, __ATOMIC_RELEASE, __HIP_MEMORY_SCOPE_AGENT);
        }
        if (cc + 1 < NCH) {
            // A/theta prefetch for next chunk
#pragma unroll
            for (int u = 0; u < CH; ++u) {
                int c = ((cc+1) << 3) + u - quad;
                c = c < 0 ? 0 : (c > MM-1 ? MM-1 : c);
                abuf[u] = A4[baseA + (size_t)c * 4];
                tbuf[u] = theta[baseA + (size_t)c * 4];
            }
            if (isCons) {
                int need = ((cc+1) << 3) + 9;          // max boundary col next chunk touches
                need = need > MM ? MM : need;
                while (__hip_atomic_load(upflag, __ATOMIC_ACQUIRE, __HIP_MEMORY_SCOPE_AGENT) < need)
                    __builtin_amdgcn_s_sleep(1);
#pragma unroll
                for (int u = 0; u < CH; ++u) {
                    int col = ((cc+1) << 3) + 2 + u;
                    col = col > MM ? MM : col;
                    bw[u] = B4[col - 1];
                }
#pragma unroll
                for (int u = 0; u < CH; ++u)
                    bmx[u] = fmaxf(fmaxf(bw[u].x,bw[u].y), fmaxf(bw[u].z,bw[u].w));
            }
        }
    }
}

extern "C" void kernel_launch(void* const* d_in, const int* in_sizes, int n_in,
                              void* d_out, int out_size, void* d_ws, size_t ws_size,
                              hipStream_t stream) {
    const float* theta = (const float*)d_in[0];   // [1024,1024,4] f32
    const float* A     = (const float*)d_in[1];   // [1024,1024,4,4] f32
    float* out = (float*)d_out;                   // [1] f32
    // ws layout: boundary rows [63][1024] float4 (1,032,192 B), then flags [64*32] int (8 KiB).
    // ws is poisoned 0xAA each launch -> flags start negative (as int) -> consumers spin safely.
    float* bnd = (float*)d_ws;
    int*  prog = (int*)((char*)d_ws + (size_t)63 * MM * 4 * sizeof(float));
    viterbi_pipe<<<64, 64, 0, stream>>>(theta, A, out, bnd, prog);
}

// Round 2
// 1032.313 us; speedup vs baseline: 1.2699x; 1.2699x over previous
//
#include <hip/hip_runtime.h>
#include <stdint.h>

// Softmax-Viterbi forward, 1024x1024 grid, S=4, strip-pipelined wavefront.
//
// R1 -> R2 changes:
//  * Handoff no longer uses acquire/release agent atomics (those emit
//    buffer_wbl2 sc1 / buffer_inv sc1 on gfx95x = full-L2 writeback/invalidate
//    per chunk -> measured 99% idle). Instead: RELAXED agent-scope atomics for
//    boundary data + flags (sc0/sc1 ops that bypass L1/L2 and hit the coherent
//    IF point directly), with explicit `s_waitcnt vmcnt(0)` ordering data
//    before flag on the producer, and a compiler barrier after the consumer
//    spin. Release/acquire semantics without any cache maintenance.
//  * Cross-quad movement: 8 parallel ds_bpermutes straight from wn (collect
//    own quad AND quad-above in one stage) instead of collect-then-shfl_up
//    (two dependent ds stages) -> ~40 cyc off the per-step chain.

#define NN 1024
#define MM 1024
#define LOG2E 1.4426950408889634f
#define LN2f  0.6931471805599453f
#define NEG_S (-1.4426950408889634e8f)   // log2e * (-1e8)
#define CH 8
#define NCH 130                           // tau = 0..1039

__device__ __forceinline__ float ld_coh(const float* p) {
    return __hip_atomic_load(p, __ATOMIC_RELAXED, __HIP_MEMORY_SCOPE_AGENT);
}
__device__ __forceinline__ void st_coh(float* p, float v) {
    __hip_atomic_store(p, v, __ATOMIC_RELAXED, __HIP_MEMORY_SCOPE_AGENT);
}

__global__ __launch_bounds__(64, 1) void viterbi_pipe(
    const float* __restrict__ theta, const float* __restrict__ A,
    float* __restrict__ out, float* __restrict__ bnd, int* __restrict__ prog)
{
    const int lane = threadIdx.x & 63;
    const int quad = lane >> 2;           // row within strip (0..15)
    const int t    = lane & 3;            // target state (m,x,y,s)
    const int bid  = blockIdx.x;
    const int strip = ((bid & 7) << 3) | (bid >> 3);   // XCD swizzle
    const int r = (strip << 4) + quad;
    const bool isCons = (strip > 0);
    const bool isProd = (strip < 63);

    const float4* A4 = (const float4*)A;
    const size_t baseA = ((size_t)r * MM) * 4 + t;
    const float* Bsrc = bnd + (size_t)(strip - 1) * MM * 4;  // consumer boundary rows
    float* Pst = bnd + (size_t)strip * MM * 4;               // producer boundary rows
    int* myflag = prog + strip * 32;
    int* upflag = prog + (strip - 1) * 32;

    float wq0=NEG_S,wq1=NEG_S,wq2=NEG_S,wq3=NEG_S,mq=NEG_S;
    float up0=NEG_S,up1=NEG_S,up2=NEG_S,up3=NEG_S,mu=NEG_S;
    float dg0=NEG_S,dg1=NEG_S,dg2=NEG_S,dg3=NEG_S,md=NEG_S;
    if (strip == 0 && quad == 0) { dg0=dg1=dg2=dg3=0.f; md=0.f; }

    float4 abuf[CH]; float tbuf[CH];
    float4 bw[CH];   float bmx[CH];

#pragma unroll
    for (int u = 0; u < CH; ++u) {
        int c = u - quad; c = c < 0 ? 0 : c;
        abuf[u] = A4[baseA + (size_t)c * 4];
        tbuf[u] = theta[baseA + (size_t)c * 4];
    }
    if (isCons) {
        while (__hip_atomic_load(upflag, __ATOMIC_RELAXED, __HIP_MEMORY_SCOPE_AGENT) < 9)
            __builtin_amdgcn_s_sleep(1);
        asm volatile("" ::: "memory");
        {   // col 1: initial vup for quad 0
            float b0 = ld_coh(Bsrc + 0), b1 = ld_coh(Bsrc + 1);
            float b2 = ld_coh(Bsrc + 2), b3 = ld_coh(Bsrc + 3);
            if (quad == 0) {
                up0=b0; up1=b1; up2=b2; up3=b3;
                mu = fmaxf(fmaxf(b0,b1), fmaxf(b2,b3));
            }
        }
#pragma unroll
        for (int u = 0; u < CH; ++u) {
            const float* s = Bsrc + (size_t)(1 + u) * 4;   // col 2+u (1-based), idx (2+u)-1
            bw[u].x = ld_coh(s+0); bw[u].y = ld_coh(s+1);
            bw[u].z = ld_coh(s+2); bw[u].w = ld_coh(s+3);
        }
#pragma unroll
        for (int u = 0; u < CH; ++u)
            bmx[u] = fmaxf(fmaxf(bw[u].x,bw[u].y), fmaxf(bw[u].z,bw[u].w));
    }

    const int baseLane = lane & 60;

    for (int cc = 0; cc < NCH; ++cc) {
#pragma unroll
        for (int u = 0; u < CH; ++u) {
            const int tau = (cc << 3) + u;
            const int jq  = tau - quad + 1;
            float s0 = (t==2)?wq0:((t==1)?up0:dg0);
            float s1 = (t==2)?wq1:((t==1)?up1:dg1);
            float s2 = (t==2)?wq2:((t==1)?up2:dg2);
            float s3 = (t==2)?wq3:((t==1)?up3:dg3);
            float off= (t==2)?mq :((t==1)?mu :md );
            float4 a = abuf[u];
            float e0 = exp2f(fmaf(a.x, LOG2E, s0 - off));
            float e1 = exp2f(fmaf(a.y, LOG2E, s1 - off));
            float e2 = exp2f(fmaf(a.z, LOG2E, s2 - off));
            float e3 = exp2f(fmaf(a.w, LOG2E, s3 - off));
            float L  = log2f((e0+e1)+(e2+e3));
            float wn = fmaf(tbuf[u], LOG2E, off + L);
            wn = (jq >= 1 && jq <= MM) ? wn : NEG_S;
            // one parallel bpermute stage: own quad collect + quad-above collect
            float w0 = __shfl(wn, baseLane);
            float w1 = __shfl(wn, baseLane+1);
            float w2 = __shfl(wn, baseLane+2);
            float w3 = __shfl(wn, baseLane+3);
            float u0 = __shfl(wn, baseLane-4);   // quad0: garbage, overwritten below
            float u1 = __shfl(wn, baseLane-3);
            float u2 = __shfl(wn, baseLane-2);
            float u3 = __shfl(wn, baseLane-1);
            float mn = fmaxf(fmaxf(w0,w1), fmaxf(w2,w3));
            float mun= fmaxf(fmaxf(u0,u1), fmaxf(u2,u3));
            if (quad == 15 && jq >= 1 && jq <= MM) {
                if (isProd) {
                    st_coh(&Pst[(size_t)(jq-1)*4 + t], wn);
                } else if (jq == MM) {
                    float ans = LN2f * (mn + log2f(exp2f(w0-mn)+exp2f(w1-mn)
                                                 +exp2f(w2-mn)+exp2f(w3-mn)));
                    if (t == 0) out[0] = ans;
                }
            }
            dg0=up0; dg1=up1; dg2=up2; dg3=up3; md=mu;
            up0=u0; up1=u1; up2=u2; up3=u3; mu=mun;
            if (quad == 0) {
                if (isCons) { float4 b = bw[u]; up0=b.x; up1=b.y; up2=b.z; up3=b.w; mu=bmx[u]; }
                else        { up0=NEG_S; up1=NEG_S; up2=NEG_S; up3=NEG_S; mu=NEG_S; }
            }
            wq0=w0; wq1=w1; wq2=w2; wq3=w3; mq=mn;
        }
        if (isProd) {
            int done = (cc << 3) - 7;
            if (done >= 8 && lane == 0) {
                asm volatile("s_waitcnt vmcnt(0)" ::: "memory");  // data before flag, no wbl2
                __hip_atomic_store(myflag, done, __ATOMIC_RELAXED, __HIP_MEMORY_SCOPE_AGENT);
            }
        }
        if (cc + 1 < NCH) {
#pragma unroll
            for (int u = 0; u < CH; ++u) {
                int c = ((cc+1) << 3) + u - quad;
                c = c < 0 ? 0 : (c > MM-1 ? MM-1 : c);
                abuf[u] = A4[baseA + (size_t)c * 4];
                tbuf[u] = theta[baseA + (size_t)c * 4];
            }
            if (isCons) {
                int need = ((cc+1) << 3) + 9;
                need = need > MM ? MM : need;
                while (__hip_atomic_load(upflag, __ATOMIC_RELAXED, __HIP_MEMORY_SCOPE_AGENT) < need)
                    __builtin_amdgcn_s_sleep(1);
                asm volatile("" ::: "memory");
#pragma unroll
                for (int u = 0; u < CH; ++u) {
                    int col = ((cc+1) << 3) + 2 + u;
                    col = col > MM ? MM : col;
                    const float* s = Bsrc + (size_t)(col-1) * 4;
                    bw[u].x = ld_coh(s+0); bw[u].y = ld_coh(s+1);
                    bw[u].z = ld_coh(s+2); bw[u].w = ld_coh(s+3);
                }
#pragma unroll
                for (int u = 0; u < CH; ++u)
                    bmx[u] = fmaxf(fmaxf(bw[u].x,bw[u].y), fmaxf(bw[u].z,bw[u].w));
            }
        }
    }
}

extern "C" void kernel_launch(void* const* d_in, const int* in_sizes, int n_in,
                              void* d_out, int out_size, void* d_ws, size_t ws_size,
                              hipStream_t stream) {
    const float* theta = (const float*)d_in[0];   // [1024,1024,4] f32
    const float* A     = (const float*)d_in[1];   // [1024,1024,4,4] f32
    float* out = (float*)d_out;                   // [1] f32
    float* bnd = (float*)d_ws;
    int*  prog = (int*)((char*)d_ws + (size_t)63 * MM * 4 * sizeof(float));
    viterbi_pipe<<<64, 64, 0, stream>>>(theta, A, out, bnd, prog);
}